// Round 2
// baseline (159.047 us; speedup 1.0000x reference)
//
#include <hip/hip_runtime.h>
#include <float.h>

#define NCH  128
#define TLEN 500
// p0 = 500//3 = 166, p1 = 2*500//3 = 333
// n0 = int(0.2*500) = 100, n1 = int(0.35*500) = 175
#define P0 166
#define P1 333
#define N0 100
#define N1 175

__device__ __forceinline__ float wave_sum(float v) {
#pragma unroll
    for (int m = 32; m; m >>= 1) v += __shfl_xor(v, m, 64);
    return v;
}
__device__ __forceinline__ float wave_min(float v) {
#pragma unroll
    for (int m = 32; m; m >>= 1) v = fminf(v, __shfl_xor(v, m, 64));
    return v;
}
__device__ __forceinline__ float wave_max(float v) {
#pragma unroll
    for (int m = 32; m; m >>= 1) v = fmaxf(v, __shfl_xor(v, m, 64));
    return v;
}

// One thread == one (batch, channel) row. Block of 256 threads covers 2 batches.
__global__ __launch_bounds__(256) void erp_feats_kernel(
    const float* __restrict__ eeg, float* __restrict__ out, int B) {
    const int tid = threadIdx.x;
    const int bl  = tid >> 7;          // local batch 0/1
    const int c   = tid & 127;         // channel
    const int b   = blockIdx.x * 2 + bl;

    __shared__ float s_lat[256], s_amp[256], s_n2[256], s_alpha[256], s_beta[256];

    if (b < B) {
        const float* __restrict__ ch = eeg + ((size_t)b * NCH + c) * TLEN;

        float asum  = 0.0f;            // sum x^2 over [0,166)
        float bsum  = 0.0f;            // sum x^2 over [166,333)
        float n2min = FLT_MAX;         // min over [100,175)
        float pmax  = -FLT_MAX;        // max over [166,333)
        int   pidx  = P0;              // global t of first max

        // t = 0..331 via float4 (row base is 2000B -> 16B aligned)
#pragma unroll 4
        for (int i = 0; i < 83; ++i) {
            const float4 v = *reinterpret_cast<const float4*>(ch + 4 * i);
            const float e[4] = {v.x, v.y, v.z, v.w};
            const int t0 = 4 * i;
#pragma unroll
            for (int j = 0; j < 4; ++j) {
                const int t = t0 + j;
                const float x  = e[j];
                const float xx = x * x;
                if (t < P0) asum += xx; else bsum += xx;
                if (t >= N0 && t < N1) n2min = fminf(n2min, x);
                if (t >= P0) {
                    const bool g = x > pmax;      // strict >: first occurrence wins
                    pmax = g ? x : pmax;
                    pidx = g ? t : pidx;
                }
            }
        }
        // tail element t = 332 (p300 window)
        {
            const float x = ch[332];
            bsum += x * x;
            if (x > pmax) { pmax = x; pidx = 332; }
        }

        s_lat[tid]   = (float)pidx / 100.0f;   // (p0 + peak_idx)/SFREQ, pidx is global t
        s_amp[tid]   = pmax;
        s_n2[tid]    = n2min;
        s_alpha[tid] = asum / 166.0f;          // mean over [0,166)
        s_beta[tid]  = bsum / 167.0f;          // mean over [166,333)
    }

    __syncthreads();

    // ---- channel statistics: wave 0 -> local batch 0, wave 1 -> local batch 1 ----
    const int wid  = tid >> 6;
    const int lane = tid & 63;
    if (wid < 2) {
        const int b2 = blockIdx.x * 2 + wid;
        if (b2 < B) {
            const int base = wid * 128;
            const float lat0 = s_lat[base + lane],   lat1 = s_lat[base + lane + 64];
            const float amp0 = s_amp[base + lane],   amp1 = s_amp[base + lane + 64];
            const float n20  = s_n2[base + lane],    n21  = s_n2[base + lane + 64];
            const float al0  = s_alpha[base + lane], al1  = s_alpha[base + lane + 64];
            const float be0  = s_beta[base + lane],  be1  = s_beta[base + lane + 64];

            const float inv_n = 1.0f / 128.0f;
            const float inv_m = 1.0f / 127.0f;   // ddof=1

            const float lat_mean = wave_sum(lat0 + lat1) * inv_n;
            const float amp_mean = wave_sum(amp0 + amp1) * inv_n;
            const float n2_mean  = wave_sum(n20 + n21)   * inv_n;
            const float al_mean  = wave_sum(al0 + al1)   * inv_n;
            const float be_mean  = wave_sum(be0 + be1)   * inv_n;
            const float axl_mean = wave_sum(amp0 * lat0 + amp1 * lat1) * inv_n;

            const float dl0 = lat0 - lat_mean, dl1 = lat1 - lat_mean;
            const float lat_std = sqrtf(wave_sum(dl0 * dl0 + dl1 * dl1) * inv_m);
            const float dn0 = n20 - n2_mean, dn1 = n21 - n2_mean;
            const float n2_std = sqrtf(wave_sum(dn0 * dn0 + dn1 * dn1) * inv_m);
            const float da0 = al0 - al_mean, da1 = al1 - al_mean;
            const float al_std = sqrtf(wave_sum(da0 * da0 + da1 * da1) * inv_m);
            const float db0 = be0 - be_mean, db1 = be1 - be_mean;
            const float be_std = sqrtf(wave_sum(db0 * db0 + db1 * db1) * inv_m);

            const float amp_max = wave_max(fmaxf(amp0, amp1));
            const float n2_min  = wave_min(fminf(n20, n21));
            const float al_max  = wave_max(fmaxf(al0, al1));

            if (lane == 0) {
                float* o = out + (size_t)b2 * 13;
                o[0]  = lat_mean;
                o[1]  = lat_std;
                o[2]  = amp_mean;
                o[3]  = amp_max;
                o[4]  = axl_mean;
                o[5]  = n2_mean;
                o[6]  = n2_std;
                o[7]  = n2_min;
                o[8]  = al_mean;
                o[9]  = al_std;
                o[10] = al_max;
                o[11] = be_mean;
                o[12] = be_std;
            }
        }
    }
}

extern "C" void kernel_launch(void* const* d_in, const int* in_sizes, int n_in,
                              void* d_out, int out_size, void* d_ws, size_t ws_size,
                              hipStream_t stream) {
    const float* eeg = (const float*)d_in[0];
    float* out = (float*)d_out;
    const int B = in_sizes[0] / (NCH * TLEN);   // 2048
    const int grid = (B + 1) / 2;               // 2 batches per 256-thread block
    erp_feats_kernel<<<dim3(grid), dim3(256), 0, stream>>>(eeg, out, B);
}

// Round 3
// 71.955 us; speedup vs baseline: 2.2104x; 2.2104x over previous
//
#include <hip/hip_runtime.h>
#include <float.h>

#define NCH  128
#define TLEN 500
// p0 = 500//3 = 166, p1 = 2*500//3 = 333
// n0 = int(0.2*500) = 100, n1 = int(0.35*500) = 175
#define P0 166
#define P1 333
#define N0 100
#define N1 175

__device__ __forceinline__ float wave_sum(float v) {
#pragma unroll
    for (int m = 32; m; m >>= 1) v += __shfl_xor(v, m, 64);
    return v;
}
__device__ __forceinline__ float wave_min(float v) {
#pragma unroll
    for (int m = 32; m; m >>= 1) v = fminf(v, __shfl_xor(v, m, 64));
    return v;
}
__device__ __forceinline__ float wave_max(float v) {
#pragma unroll
    for (int m = 32; m; m >>= 1) v = fmaxf(v, __shfl_xor(v, m, 64));
    return v;
}

// One block == one batch. 4 waves x 4 groups of 16 lanes; each 16-lane group
// reduces one channel per pass (8 passes -> 128 channels). Loads are 256B
// contiguous per group; butterfly is only 4 steps within the group.
__global__ __launch_bounds__(256) void erp_feats_kernel(
    const float* __restrict__ eeg, float* __restrict__ out) {
    const int b    = blockIdx.x;
    const int tid  = threadIdx.x;
    const int wid  = tid >> 6;        // wave 0..3
    const int lane = tid & 63;
    const int g    = lane >> 4;       // group 0..3 within wave
    const int l    = lane & 15;       // lane 0..15 within group

    __shared__ float s_lat[NCH], s_amp[NCH], s_n2[NCH], s_alpha[NCH], s_beta[NCH];

    const float* __restrict__ base = eeg + (size_t)b * NCH * TLEN;

#pragma unroll
    for (int p = 0; p < 8; ++p) {
        const int c = p * 16 + wid * 4 + g;
        const float* __restrict__ ch = base + (size_t)c * TLEN;

        float asum  = 0.0f;           // sum x^2 over [0,166)
        float bsum  = 0.0f;           // sum x^2 over [166,333)
        float n2min = FLT_MAX;        // min over [100,175)
        float pmax  = -FLT_MAX;       // max over [166,333)
        int   pidx  = P0;             // global t of first max

        // k = 0..4: float4 index i = 16k + l in [0,80) -> t in [0,320), all valid
#pragma unroll
        for (int k = 0; k < 5; ++k) {
            const int i = k * 16 + l;
            const float4 v = *reinterpret_cast<const float4*>(ch + 4 * i);
            const float e[4] = {v.x, v.y, v.z, v.w};
            const int t0 = 4 * i;
#pragma unroll
            for (int j = 0; j < 4; ++j) {
                const int t = t0 + j;
                const float x  = e[j];
                const float xx = x * x;
                if (t < P0) {
                    asum += xx;
                } else {
                    bsum += xx;
                    if (x > pmax) { pmax = x; pidx = t; }   // strict >: first occurrence
                }
                if (t >= N0 && t < N1) n2min = fminf(n2min, x);
            }
        }
        // tail: i = 80 + l for l < 4 -> t in [320,336), keep t < 333
        if (l < 4) {
            const int i = 80 + l;
            const float4 v = *reinterpret_cast<const float4*>(ch + 4 * i);
            const float e[4] = {v.x, v.y, v.z, v.w};
            const int t0 = 4 * i;
#pragma unroll
            for (int j = 0; j < 4; ++j) {
                const int t = t0 + j;
                if (t < P1) {
                    const float x = e[j];
                    bsum += x * x;
                    if (x > pmax) { pmax = x; pidx = t; }
                }
            }
        }

        // 16-lane butterfly (masks 8,4,2,1 stay within the group)
#pragma unroll
        for (int m = 8; m; m >>= 1) {
            asum  += __shfl_xor(asum, m, 64);
            bsum  += __shfl_xor(bsum, m, 64);
            n2min  = fminf(n2min, __shfl_xor(n2min, m, 64));
            const float om = __shfl_xor(pmax, m, 64);
            const int   oi = __shfl_xor(pidx, m, 64);
            if (om > pmax || (om == pmax && oi < pidx)) { pmax = om; pidx = oi; }
        }

        if (l == 0) {
            s_lat[c]   = (float)pidx / 100.0f;   // (p0 + peak_idx)/SFREQ, pidx is global t
            s_amp[c]   = pmax;
            s_n2[c]    = n2min;
            s_alpha[c] = asum / 166.0f;          // mean over [0,166)
            s_beta[c]  = bsum / 167.0f;          // mean over [166,333)
        }
    }

    __syncthreads();

    // ---- channel statistics (wave 0 only; lane handles ch lane and lane+64) ----
    if (wid == 0) {
        const float lat0 = s_lat[lane],   lat1 = s_lat[lane + 64];
        const float amp0 = s_amp[lane],   amp1 = s_amp[lane + 64];
        const float n20  = s_n2[lane],    n21  = s_n2[lane + 64];
        const float al0  = s_alpha[lane], al1  = s_alpha[lane + 64];
        const float be0  = s_beta[lane],  be1  = s_beta[lane + 64];

        const float inv_n = 1.0f / 128.0f;
        const float inv_m = 1.0f / 127.0f;   // ddof=1

        const float lat_mean = wave_sum(lat0 + lat1) * inv_n;
        const float amp_mean = wave_sum(amp0 + amp1) * inv_n;
        const float n2_mean  = wave_sum(n20 + n21)   * inv_n;
        const float al_mean  = wave_sum(al0 + al1)   * inv_n;
        const float be_mean  = wave_sum(be0 + be1)   * inv_n;
        const float axl_mean = wave_sum(amp0 * lat0 + amp1 * lat1) * inv_n;

        const float dl0 = lat0 - lat_mean, dl1 = lat1 - lat_mean;
        const float lat_std = sqrtf(wave_sum(dl0 * dl0 + dl1 * dl1) * inv_m);
        const float dn0 = n20 - n2_mean, dn1 = n21 - n2_mean;
        const float n2_std = sqrtf(wave_sum(dn0 * dn0 + dn1 * dn1) * inv_m);
        const float da0 = al0 - al_mean, da1 = al1 - al_mean;
        const float al_std = sqrtf(wave_sum(da0 * da0 + da1 * da1) * inv_m);
        const float db0 = be0 - be_mean, db1 = be1 - be_mean;
        const float be_std = sqrtf(wave_sum(db0 * db0 + db1 * db1) * inv_m);

        const float amp_max = wave_max(fmaxf(amp0, amp1));
        const float n2_min  = wave_min(fminf(n20, n21));
        const float al_max  = wave_max(fmaxf(al0, al1));

        if (lane == 0) {
            float* o = out + (size_t)b * 13;
            o[0]  = lat_mean;
            o[1]  = lat_std;
            o[2]  = amp_mean;
            o[3]  = amp_max;
            o[4]  = axl_mean;
            o[5]  = n2_mean;
            o[6]  = n2_std;
            o[7]  = n2_min;
            o[8]  = al_mean;
            o[9]  = al_std;
            o[10] = al_max;
            o[11] = be_mean;
            o[12] = be_std;
        }
    }
}

extern "C" void kernel_launch(void* const* d_in, const int* in_sizes, int n_in,
                              void* d_out, int out_size, void* d_ws, size_t ws_size,
                              hipStream_t stream) {
    const float* eeg = (const float*)d_in[0];
    float* out = (float*)d_out;
    const int B = in_sizes[0] / (NCH * TLEN);   // 2048
    erp_feats_kernel<<<dim3(B), dim3(256), 0, stream>>>(eeg, out);
}